// Round 1
// baseline (1691.063 us; speedup 1.0000x reference)
//
#include <hip/hip_runtime.h>
#include <math.h>

#define N_NODES 100000
#define N_EDGES 3200000
#define FIN     1433

// ---------------- zero ----------------
__global__ void k_zero(int* __restrict__ p, int n) {
  int i = blockIdx.x * blockDim.x + threadIdx.x;
  if (i < n) p[i] = 0;
}

// ---------------- histogram of destinations ----------------
__global__ void k_hist(const int* __restrict__ row, int* __restrict__ cnt) {
  int e = blockIdx.x * blockDim.x + threadIdx.x;
  if (e < N_EDGES) atomicAdd(&cnt[row[e]], 1);
}

// ---------------- dinv = 1/sqrt(deg+1)  (self-loop) ----------------
__global__ void k_dinv(const int* __restrict__ cnt, float* __restrict__ dinv) {
  int i = blockIdx.x * blockDim.x + threadIdx.x;
  if (i < N_NODES) dinv[i] = 1.0f / sqrtf((float)(cnt[i] + 1));
}

// ---------------- 3-phase exclusive scan (1024 elems/block) ----------------
__global__ void k_scanA(const int* __restrict__ cnt, int* __restrict__ bsum) {
  __shared__ int sd[256];
  int t = threadIdx.x, b = blockIdx.x;
  int base = b * 1024 + t * 4;
  int s = 0;
#pragma unroll
  for (int m = 0; m < 4; m++) {
    int i = base + m;
    if (i < N_NODES) s += cnt[i];
  }
  sd[t] = s; __syncthreads();
  for (int off = 128; off > 0; off >>= 1) {
    if (t < off) sd[t] += sd[t + off];
    __syncthreads();
  }
  if (t == 0) bsum[b] = sd[0];
}

__global__ void k_scanB(int* __restrict__ bsum, int* __restrict__ rowStart, int nb) {
  __shared__ int sd[128];
  int t = threadIdx.x;
  int v = (t < nb) ? bsum[t] : 0;
  sd[t] = v;
  __syncthreads();
  for (int off = 1; off < 128; off <<= 1) {
    int add = (t >= off) ? sd[t - off] : 0;
    __syncthreads();
    sd[t] += add;
    __syncthreads();
  }
  if (t < nb) bsum[t] = (t == 0) ? 0 : sd[t - 1];
  if (t == 0) rowStart[N_NODES] = sd[nb - 1];
}

__global__ void k_scanC(const int* __restrict__ cnt, const int* __restrict__ bsum,
                        int* __restrict__ rowStart) {
  __shared__ int sd[256];
  int t = threadIdx.x, b = blockIdx.x;
  int base = b * 1024 + t * 4;
  int v[4], pre[4], s = 0;
#pragma unroll
  for (int m = 0; m < 4; m++) {
    int i = base + m;
    v[m] = (i < N_NODES) ? cnt[i] : 0;
    pre[m] = s; s += v[m];
  }
  sd[t] = s; __syncthreads();
  for (int off = 1; off < 256; off <<= 1) {
    int add = (t >= off) ? sd[t - off] : 0;
    __syncthreads();
    sd[t] += add;
    __syncthreads();
  }
  int ex = (t == 0) ? 0 : sd[t - 1];
  int base0 = bsum[b] + ex;
#pragma unroll
  for (int m = 0; m < 4; m++) {
    int i = base + m;
    if (i < N_NODES) rowStart[i] = base0 + pre[m];
  }
}

// ---------------- scatter edges into CSR ----------------
__global__ void k_scatter(const int* __restrict__ row, const int* __restrict__ col,
                          const int* __restrict__ rowStart, int* __restrict__ fill,
                          int* __restrict__ colc) {
  int e = blockIdx.x * blockDim.x + threadIdx.x;
  if (e < N_EDGES) {
    int r = row[e];
    int pos = rowStart[r] + atomicAdd(&fill[r], 1);
    colc[pos] = col[e];
  }
}

// ---------------- GEMM1: t1 = x @ W1   (100000x1433 @ 1433x16) ----------------
// One wave per block; thread-per-row; LDS-staged x tile (coalesced loads);
// W1 access is wave-uniform -> scalar loads.
#define KC 64
__global__ __launch_bounds__(64) void k_gemm1(const float* __restrict__ x,
                                              const float* __restrict__ W1,
                                              float* __restrict__ t1) {
  __shared__ float xs[64][KC + 1];
  int t = threadIdx.x;
  int rb = blockIdx.x * 64;
  int rowi = rb + t;
  float acc[16];
#pragma unroll
  for (int j = 0; j < 16; j++) acc[j] = 0.0f;

  for (int kc = 0; kc < FIN; kc += KC) {
    int kl = FIN - kc; if (kl > KC) kl = KC;
    __syncthreads();
    // stage: thread t loads column (kc+t) for each of the 64 rows (coalesced)
    for (int rl = 0; rl < 64; rl++) {
      int gr = rb + rl;
      float v = 0.0f;
      if (gr < N_NODES && t < kl) v = x[(size_t)gr * FIN + kc + t];
      xs[rl][t] = v;
    }
    __syncthreads();
#pragma unroll 4
    for (int k = 0; k < kl; k++) {
      float xv = xs[t][k];
      const float* w = &W1[(size_t)(kc + k) * 16];  // wave-uniform
#pragma unroll
      for (int j = 0; j < 16; j++) acc[j] = fmaf(xv, w[j], acc[j]);
    }
  }
  if (rowi < N_NODES) {
    float* o = t1 + (size_t)rowi * 16;
#pragma unroll
    for (int j = 0; j < 16; j++) o[j] = acc[j];
  }
}

// ---------------- agg1: h1r = relu(dinv_i*(sum dinv_c*t1[c] + dinv_i*t1[i]) + b1) ----
// Wave per node; 4 lanes per edge (each lane a float4 slice), 16 edge slots.
__global__ __launch_bounds__(256) void k_agg1(const float* __restrict__ t1,
                                              const int* __restrict__ rowStart,
                                              const int* __restrict__ colc,
                                              const float* __restrict__ dinv,
                                              const float* __restrict__ b1,
                                              float* __restrict__ h1r) {
  int lane = threadIdx.x & 63;
  int wid  = threadIdx.x >> 6;
  int node = blockIdx.x * 4 + wid;
  if (node >= N_NODES) return;
  int q = lane & 3, slot = lane >> 2;
  int s0 = rowStart[node], s1 = rowStart[node + 1];
  float ax = 0.f, ay = 0.f, az = 0.f, aw = 0.f;
  for (int e = s0 + slot; e < s1; e += 16) {
    int c = colc[e];
    float w = dinv[c];
    float4 v = *(const float4*)(t1 + (size_t)c * 16 + q * 4);
    ax = fmaf(v.x, w, ax); ay = fmaf(v.y, w, ay);
    az = fmaf(v.z, w, az); aw = fmaf(v.w, w, aw);
  }
#pragma unroll
  for (int off = 4; off < 64; off <<= 1) {
    ax += __shfl_xor(ax, off, 64);
    ay += __shfl_xor(ay, off, 64);
    az += __shfl_xor(az, off, 64);
    aw += __shfl_xor(aw, off, 64);
  }
  float di = dinv[node];
  if (slot == 0) {
    float4 sv = *(const float4*)(t1 + (size_t)node * 16 + q * 4);
    float4 bb = *(const float4*)(b1 + q * 4);
    float4 o;
    o.x = fmaxf(0.f, di * (ax + di * sv.x) + bb.x);
    o.y = fmaxf(0.f, di * (ay + di * sv.y) + bb.y);
    o.z = fmaxf(0.f, di * (az + di * sv.z) + bb.z);
    o.w = fmaxf(0.f, di * (aw + di * sv.w) + bb.w);
    *(float4*)(h1r + (size_t)node * 16 + q * 4) = o;
  }
}

// ---------------- GEMM2: t2 = h1r @ W2  (padded to 8 cols) ----------------
__global__ void k_gemm2(const float* __restrict__ h1r, const float* __restrict__ W2,
                        float* __restrict__ t2) {
  int i = blockIdx.x * blockDim.x + threadIdx.x;
  if (i >= N_NODES) return;
  float h[16];
#pragma unroll
  for (int k = 0; k < 16; k++) h[k] = h1r[(size_t)i * 16 + k];
  float a[7] = {0, 0, 0, 0, 0, 0, 0};
#pragma unroll
  for (int k = 0; k < 16; k++)
#pragma unroll
    for (int j = 0; j < 7; j++) a[j] = fmaf(h[k], W2[k * 7 + j], a[j]);
  float* o = t2 + (size_t)i * 8;
#pragma unroll
  for (int j = 0; j < 7; j++) o[j] = a[j];
  o[7] = 0.0f;
}

// ---------------- agg2 + bias + log_softmax -> out ----------------
// Wave per node; 2 lanes per edge (float4 halves of padded 8), 32 edge slots.
__global__ __launch_bounds__(256) void k_agg2(const float* __restrict__ t2,
                                              const int* __restrict__ rowStart,
                                              const int* __restrict__ colc,
                                              const float* __restrict__ dinv,
                                              const float* __restrict__ b2,
                                              float* __restrict__ out) {
  int lane = threadIdx.x & 63;
  int wid  = threadIdx.x >> 6;
  int node = blockIdx.x * 4 + wid;
  if (node >= N_NODES) return;
  int q = lane & 1, slot = lane >> 1;
  int s0 = rowStart[node], s1 = rowStart[node + 1];
  float ax = 0.f, ay = 0.f, az = 0.f, aw = 0.f;
  for (int e = s0 + slot; e < s1; e += 32) {
    int c = colc[e];
    float w = dinv[c];
    float4 v = *(const float4*)(t2 + (size_t)c * 8 + q * 4);
    ax = fmaf(v.x, w, ax); ay = fmaf(v.y, w, ay);
    az = fmaf(v.z, w, az); aw = fmaf(v.w, w, aw);
  }
#pragma unroll
  for (int off = 2; off < 64; off <<= 1) {
    ax += __shfl_xor(ax, off, 64);
    ay += __shfl_xor(ay, off, 64);
    az += __shfl_xor(az, off, 64);
    aw += __shfl_xor(aw, off, 64);
  }
  float di = dinv[node];
  float4 sv = *(const float4*)(t2 + (size_t)node * 8 + q * 4);
  float lg[4];
  float am[4] = {ax, ay, az, aw};
  float sm[4] = {sv.x, sv.y, sv.z, sv.w};
#pragma unroll
  for (int m = 0; m < 4; m++) {
    int j = 4 * q + m;
    float bb = (j < 7) ? b2[j] : 0.0f;
    lg[m] = di * (am[m] + di * sm[m]) + bb;
    if (j == 7) lg[m] = -1e30f;
  }
  // exchange halves: q=0 lanes receive logits 4..6 from q=1 partner
  float o4 = __shfl_xor(lg[0], 1, 64);
  float o5 = __shfl_xor(lg[1], 1, 64);
  float o6 = __shfl_xor(lg[2], 1, 64);
  if (lane == 0) {
    float a[7] = {lg[0], lg[1], lg[2], lg[3], o4, o5, o6};
    float mx = a[0];
#pragma unroll
    for (int j = 1; j < 7; j++) mx = fmaxf(mx, a[j]);
    float s = 0.f;
#pragma unroll
    for (int j = 0; j < 7; j++) s += expf(a[j] - mx);
    float lse = mx + logf(s);
    float* o = out + (size_t)node * 7;
#pragma unroll
    for (int j = 0; j < 7; j++) o[j] = a[j] - lse;
  }
}

extern "C" void kernel_launch(void* const* d_in, const int* in_sizes, int n_in,
                              void* d_out, int out_size, void* d_ws, size_t ws_size,
                              hipStream_t stream) {
  const float* x   = (const float*)d_in[0];
  const int*   row = (const int*)d_in[1];
  const int*   col = (const int*)d_in[2];
  const float* W1  = (const float*)d_in[3];
  const float* b1  = (const float*)d_in[4];
  const float* W2  = (const float*)d_in[5];
  const float* b2  = (const float*)d_in[6];
  float* out = (float*)d_out;

  char* w = (char*)d_ws;
  auto alloc = [&](size_t bytes) {
    char* p = w;
    w += (bytes + 255) & ~(size_t)255;
    return p;
  };
  int*   cnt      = (int*)alloc((size_t)N_NODES * 4);
  int*   fill     = (int*)alloc((size_t)N_NODES * 4);
  int*   rowStart = (int*)alloc((size_t)(N_NODES + 1) * 4);
  int*   bsum     = (int*)alloc(128 * 4);
  float* dinv     = (float*)alloc((size_t)N_NODES * 4);
  int*   colc     = (int*)alloc((size_t)N_EDGES * 4);
  float* t1       = (float*)alloc((size_t)N_NODES * 16 * 4);
  float* h1r      = (float*)alloc((size_t)N_NODES * 16 * 4);
  float* t2       = (float*)alloc((size_t)N_NODES * 8 * 4);

  const int NB = (N_NODES + 1023) / 1024;  // 98

  k_zero<<<(N_NODES + 255) / 256, 256, 0, stream>>>(cnt, N_NODES);
  k_zero<<<(N_NODES + 255) / 256, 256, 0, stream>>>(fill, N_NODES);
  k_hist<<<(N_EDGES + 255) / 256, 256, 0, stream>>>(row, cnt);
  k_dinv<<<(N_NODES + 255) / 256, 256, 0, stream>>>(cnt, dinv);
  k_scanA<<<NB, 256, 0, stream>>>(cnt, bsum);
  k_scanB<<<1, 128, 0, stream>>>(bsum, rowStart, NB);
  k_scanC<<<NB, 256, 0, stream>>>(cnt, bsum, rowStart);
  k_scatter<<<(N_EDGES + 255) / 256, 256, 0, stream>>>(row, col, rowStart, fill, colc);
  k_gemm1<<<(N_NODES + 63) / 64, 64, 0, stream>>>(x, W1, t1);
  k_agg1<<<(N_NODES + 3) / 4, 256, 0, stream>>>(t1, rowStart, colc, dinv, b1, h1r);
  k_gemm2<<<(N_NODES + 255) / 256, 256, 0, stream>>>(h1r, W2, t2);
  k_agg2<<<(N_NODES + 3) / 4, 256, 0, stream>>>(t2, rowStart, colc, dinv, b2, out);
}

// Round 2
// 1214.277 us; speedup vs baseline: 1.3927x; 1.3927x over previous
//
#include <hip/hip_runtime.h>
#include <math.h>

#define N_NODES 100000
#define N_EDGES 3200000
#define FIN     1433

// ---------------- zero ----------------
__global__ void k_zero(int* __restrict__ p, int n) {
  int i = blockIdx.x * blockDim.x + threadIdx.x;
  if (i < n) p[i] = 0;
}

// ---------------- histogram of destinations ----------------
__global__ void k_hist(const int* __restrict__ row, int* __restrict__ cnt) {
  int e = blockIdx.x * blockDim.x + threadIdx.x;
  if (e < N_EDGES) atomicAdd(&cnt[row[e]], 1);
}

// ---------------- dinv = 1/sqrt(deg+1)  (self-loop) ----------------
__global__ void k_dinv(const int* __restrict__ cnt, float* __restrict__ dinv) {
  int i = blockIdx.x * blockDim.x + threadIdx.x;
  if (i < N_NODES) dinv[i] = 1.0f / sqrtf((float)(cnt[i] + 1));
}

// ---------------- 3-phase exclusive scan (1024 elems/block) ----------------
__global__ void k_scanA(const int* __restrict__ cnt, int* __restrict__ bsum) {
  __shared__ int sd[256];
  int t = threadIdx.x, b = blockIdx.x;
  int base = b * 1024 + t * 4;
  int s = 0;
#pragma unroll
  for (int m = 0; m < 4; m++) {
    int i = base + m;
    if (i < N_NODES) s += cnt[i];
  }
  sd[t] = s; __syncthreads();
  for (int off = 128; off > 0; off >>= 1) {
    if (t < off) sd[t] += sd[t + off];
    __syncthreads();
  }
  if (t == 0) bsum[b] = sd[0];
}

__global__ void k_scanB(int* __restrict__ bsum, int* __restrict__ rowStart, int nb) {
  __shared__ int sd[128];
  int t = threadIdx.x;
  int v = (t < nb) ? bsum[t] : 0;
  sd[t] = v;
  __syncthreads();
  for (int off = 1; off < 128; off <<= 1) {
    int add = (t >= off) ? sd[t - off] : 0;
    __syncthreads();
    sd[t] += add;
    __syncthreads();
  }
  if (t < nb) bsum[t] = (t == 0) ? 0 : sd[t - 1];
  if (t == 0) rowStart[N_NODES] = sd[nb - 1];
}

__global__ void k_scanC(const int* __restrict__ cnt, const int* __restrict__ bsum,
                        int* __restrict__ rowStart) {
  __shared__ int sd[256];
  int t = threadIdx.x, b = blockIdx.x;
  int base = b * 1024 + t * 4;
  int v[4], pre[4], s = 0;
#pragma unroll
  for (int m = 0; m < 4; m++) {
    int i = base + m;
    v[m] = (i < N_NODES) ? cnt[i] : 0;
    pre[m] = s; s += v[m];
  }
  sd[t] = s; __syncthreads();
  for (int off = 1; off < 256; off <<= 1) {
    int add = (t >= off) ? sd[t - off] : 0;
    __syncthreads();
    sd[t] += add;
    __syncthreads();
  }
  int ex = (t == 0) ? 0 : sd[t - 1];
  int base0 = bsum[b] + ex;
#pragma unroll
  for (int m = 0; m < 4; m++) {
    int i = base + m;
    if (i < N_NODES) rowStart[i] = base0 + pre[m];
  }
}

// ---------------- scatter edges into CSR ----------------
__global__ void k_scatter(const int* __restrict__ row, const int* __restrict__ col,
                          const int* __restrict__ rowStart, int* __restrict__ fill,
                          int* __restrict__ colc) {
  int e = blockIdx.x * blockDim.x + threadIdx.x;
  if (e < N_EDGES) {
    int r = row[e];
    int pos = rowStart[r] + atomicAdd(&fill[r], 1);
    colc[pos] = col[e];
  }
}

// ---------------- GEMM1: t1 = x @ W1   (100000x1433 @ 1433x16) ----------------
// Thread-per-row, register double-buffered streaming of the row (8 float4
// loads in flight while 512 FMAs execute). W1 addresses are lane-uniform ->
// scalar loads. No LDS, no barriers. block=64 for even CU balance.
__global__ __launch_bounds__(64) void k_gemm1(const float* __restrict__ x,
                                              const float* __restrict__ W1,
                                              float* __restrict__ t1) {
  int rowi = blockIdx.x * 64 + threadIdx.x;
  if (rowi >= N_NODES) return;
  const float* __restrict__ xr = x + (size_t)rowi * FIN;

  float acc[16];
#pragma unroll
  for (int j = 0; j < 16; j++) acc[j] = 0.0f;

  float4 buf[8], nbuf[8];
#pragma unroll
  for (int m = 0; m < 8; m++) buf[m] = *(const float4*)(xr + m * 4);

  const int NCH = 44;  // 44*32 = 1408
  for (int ch = 0; ch < NCH; ch++) {
    int kc = ch * 32;
    if (ch + 1 < NCH) {
#pragma unroll
      for (int m = 0; m < 8; m++) nbuf[m] = *(const float4*)(xr + kc + 32 + m * 4);
    }
#pragma unroll
    for (int m = 0; m < 8; m++) {
      float xv0 = buf[m].x, xv1 = buf[m].y, xv2 = buf[m].z, xv3 = buf[m].w;
      const float* w0 = &W1[(size_t)(kc + m * 4 + 0) * 16];
      const float* w1 = &W1[(size_t)(kc + m * 4 + 1) * 16];
      const float* w2 = &W1[(size_t)(kc + m * 4 + 2) * 16];
      const float* w3 = &W1[(size_t)(kc + m * 4 + 3) * 16];
#pragma unroll
      for (int j = 0; j < 16; j++) {
        acc[j] = fmaf(xv0, w0[j], acc[j]);
        acc[j] = fmaf(xv1, w1[j], acc[j]);
        acc[j] = fmaf(xv2, w2[j], acc[j]);
        acc[j] = fmaf(xv3, w3[j], acc[j]);
      }
    }
#pragma unroll
    for (int m = 0; m < 8; m++) buf[m] = nbuf[m];
  }
  // tail: k = 1408..1432
  for (int k = 1408; k < FIN; k++) {
    float xv = xr[k];
    const float* w = &W1[(size_t)k * 16];
#pragma unroll
    for (int j = 0; j < 16; j++) acc[j] = fmaf(xv, w[j], acc[j]);
  }

  float* o = t1 + (size_t)rowi * 16;
#pragma unroll
  for (int j = 0; j < 16; j += 4)
    *(float4*)(o + j) = make_float4(acc[j], acc[j + 1], acc[j + 2], acc[j + 3]);
}

// ---------------- agg1: h1r = relu(dinv_i*(sum dinv_c*t1[c] + dinv_i*t1[i]) + b1) ----
// Wave per node; 4 lanes per edge (each lane a float4 slice), 16 edge slots.
__global__ __launch_bounds__(256) void k_agg1(const float* __restrict__ t1,
                                              const int* __restrict__ rowStart,
                                              const int* __restrict__ colc,
                                              const float* __restrict__ dinv,
                                              const float* __restrict__ b1,
                                              float* __restrict__ h1r) {
  int lane = threadIdx.x & 63;
  int wid  = threadIdx.x >> 6;
  int node = blockIdx.x * 4 + wid;
  if (node >= N_NODES) return;
  int q = lane & 3, slot = lane >> 2;
  int s0 = rowStart[node], s1 = rowStart[node + 1];
  float ax = 0.f, ay = 0.f, az = 0.f, aw = 0.f;
  for (int e = s0 + slot; e < s1; e += 16) {
    int c = colc[e];
    float w = dinv[c];
    float4 v = *(const float4*)(t1 + (size_t)c * 16 + q * 4);
    ax = fmaf(v.x, w, ax); ay = fmaf(v.y, w, ay);
    az = fmaf(v.z, w, az); aw = fmaf(v.w, w, aw);
  }
#pragma unroll
  for (int off = 4; off < 64; off <<= 1) {
    ax += __shfl_xor(ax, off, 64);
    ay += __shfl_xor(ay, off, 64);
    az += __shfl_xor(az, off, 64);
    aw += __shfl_xor(aw, off, 64);
  }
  float di = dinv[node];
  if (slot == 0) {
    float4 sv = *(const float4*)(t1 + (size_t)node * 16 + q * 4);
    float4 bb = *(const float4*)(b1 + q * 4);
    float4 o;
    o.x = fmaxf(0.f, di * (ax + di * sv.x) + bb.x);
    o.y = fmaxf(0.f, di * (ay + di * sv.y) + bb.y);
    o.z = fmaxf(0.f, di * (az + di * sv.z) + bb.z);
    o.w = fmaxf(0.f, di * (aw + di * sv.w) + bb.w);
    *(float4*)(h1r + (size_t)node * 16 + q * 4) = o;
  }
}

// ---------------- GEMM2: t2 = h1r @ W2  (padded to 8 cols) ----------------
__global__ void k_gemm2(const float* __restrict__ h1r, const float* __restrict__ W2,
                        float* __restrict__ t2) {
  int i = blockIdx.x * blockDim.x + threadIdx.x;
  if (i >= N_NODES) return;
  float h[16];
#pragma unroll
  for (int k = 0; k < 16; k++) h[k] = h1r[(size_t)i * 16 + k];
  float a[7] = {0, 0, 0, 0, 0, 0, 0};
#pragma unroll
  for (int k = 0; k < 16; k++)
#pragma unroll
    for (int j = 0; j < 7; j++) a[j] = fmaf(h[k], W2[k * 7 + j], a[j]);
  float* o = t2 + (size_t)i * 8;
#pragma unroll
  for (int j = 0; j < 7; j++) o[j] = a[j];
  o[7] = 0.0f;
}

// ---------------- agg2 + bias + log_softmax -> out ----------------
// Wave per node; 2 lanes per edge (float4 halves of padded 8), 32 edge slots.
__global__ __launch_bounds__(256) void k_agg2(const float* __restrict__ t2,
                                              const int* __restrict__ rowStart,
                                              const int* __restrict__ colc,
                                              const float* __restrict__ dinv,
                                              const float* __restrict__ b2,
                                              float* __restrict__ out) {
  int lane = threadIdx.x & 63;
  int wid  = threadIdx.x >> 6;
  int node = blockIdx.x * 4 + wid;
  if (node >= N_NODES) return;
  int q = lane & 1, slot = lane >> 1;
  int s0 = rowStart[node], s1 = rowStart[node + 1];
  float ax = 0.f, ay = 0.f, az = 0.f, aw = 0.f;
  for (int e = s0 + slot; e < s1; e += 32) {
    int c = colc[e];
    float w = dinv[c];
    float4 v = *(const float4*)(t2 + (size_t)c * 8 + q * 4);
    ax = fmaf(v.x, w, ax); ay = fmaf(v.y, w, ay);
    az = fmaf(v.z, w, az); aw = fmaf(v.w, w, aw);
  }
#pragma unroll
  for (int off = 2; off < 64; off <<= 1) {
    ax += __shfl_xor(ax, off, 64);
    ay += __shfl_xor(ay, off, 64);
    az += __shfl_xor(az, off, 64);
    aw += __shfl_xor(aw, off, 64);
  }
  float di = dinv[node];
  float4 sv = *(const float4*)(t2 + (size_t)node * 8 + q * 4);
  float lg[4];
  float am[4] = {ax, ay, az, aw};
  float sm[4] = {sv.x, sv.y, sv.z, sv.w};
#pragma unroll
  for (int m = 0; m < 4; m++) {
    int j = 4 * q + m;
    float bb = (j < 7) ? b2[j] : 0.0f;
    lg[m] = di * (am[m] + di * sm[m]) + bb;
    if (j == 7) lg[m] = -1e30f;
  }
  // exchange halves: q=0 lanes receive logits 4..6 from q=1 partner
  float o4 = __shfl_xor(lg[0], 1, 64);
  float o5 = __shfl_xor(lg[1], 1, 64);
  float o6 = __shfl_xor(lg[2], 1, 64);
  if (lane == 0) {
    float a[7] = {lg[0], lg[1], lg[2], lg[3], o4, o5, o6};
    float mx = a[0];
#pragma unroll
    for (int j = 1; j < 7; j++) mx = fmaxf(mx, a[j]);
    float s = 0.f;
#pragma unroll
    for (int j = 0; j < 7; j++) s += expf(a[j] - mx);
    float lse = mx + logf(s);
    float* o = out + (size_t)node * 7;
#pragma unroll
    for (int j = 0; j < 7; j++) o[j] = a[j] - lse;
  }
}

extern "C" void kernel_launch(void* const* d_in, const int* in_sizes, int n_in,
                              void* d_out, int out_size, void* d_ws, size_t ws_size,
                              hipStream_t stream) {
  const float* x   = (const float*)d_in[0];
  const int*   row = (const int*)d_in[1];
  const int*   col = (const int*)d_in[2];
  const float* W1  = (const float*)d_in[3];
  const float* b1  = (const float*)d_in[4];
  const float* W2  = (const float*)d_in[5];
  const float* b2  = (const float*)d_in[6];
  float* out = (float*)d_out;

  char* w = (char*)d_ws;
  auto alloc = [&](size_t bytes) {
    char* p = w;
    w += (bytes + 255) & ~(size_t)255;
    return p;
  };
  int*   cnt      = (int*)alloc((size_t)N_NODES * 4);
  int*   fill     = (int*)alloc((size_t)N_NODES * 4);
  int*   rowStart = (int*)alloc((size_t)(N_NODES + 1) * 4);
  int*   bsum     = (int*)alloc(128 * 4);
  float* dinv     = (float*)alloc((size_t)N_NODES * 4);
  int*   colc     = (int*)alloc((size_t)N_EDGES * 4);
  float* t1       = (float*)alloc((size_t)N_NODES * 16 * 4);
  float* h1r      = (float*)alloc((size_t)N_NODES * 16 * 4);
  float* t2       = (float*)alloc((size_t)N_NODES * 8 * 4);

  const int NB = (N_NODES + 1023) / 1024;  // 98

  k_zero<<<(N_NODES + 255) / 256, 256, 0, stream>>>(cnt, N_NODES);
  k_zero<<<(N_NODES + 255) / 256, 256, 0, stream>>>(fill, N_NODES);
  k_hist<<<(N_EDGES + 255) / 256, 256, 0, stream>>>(row, cnt);
  k_dinv<<<(N_NODES + 255) / 256, 256, 0, stream>>>(cnt, dinv);
  k_scanA<<<NB, 256, 0, stream>>>(cnt, bsum);
  k_scanB<<<1, 128, 0, stream>>>(bsum, rowStart, NB);
  k_scanC<<<NB, 256, 0, stream>>>(cnt, bsum, rowStart);
  k_scatter<<<(N_EDGES + 255) / 256, 256, 0, stream>>>(row, col, rowStart, fill, colc);
  k_gemm1<<<(N_NODES + 63) / 64, 64, 0, stream>>>(x, W1, t1);
  k_agg1<<<(N_NODES + 3) / 4, 256, 0, stream>>>(t1, rowStart, colc, dinv, b1, h1r);
  k_gemm2<<<(N_NODES + 255) / 256, 256, 0, stream>>>(h1r, W2, t2);
  k_agg2<<<(N_NODES + 3) / 4, 256, 0, stream>>>(t2, rowStart, colc, dinv, b2, out);
}